// Round 8
// baseline (91.558 us; speedup 1.0000x reference)
//
#include <hip/hip_runtime.h>

#define MDIM 4096
#define KDIM 2048
#define UDIM 1024
#define CMOFF (MDIM * UDIM)
#define THREADS 512

typedef __bf16 bfrag __attribute__((ext_vector_type(8)));
typedef float f32x4 __attribute__((ext_vector_type(4)));

#define GLDS(gsrc, ldst)                                                                  \
  __builtin_amdgcn_global_load_lds((const __attribute__((address_space(1))) void*)(gsrc), \
                                   (__attribute__((address_space(3))) void*)(ldst), 16, 0, 0)

__device__ __forceinline__ unsigned short f2bf(float x) {
  unsigned int u = __float_as_uint(x);
  unsigned int r = (u + 0x7fffu + ((u >> 16) & 1u)) >> 16;
  return (unsigned short)r;
}

__device__ __forceinline__ float fast_sigmoid(float x) { return 1.f / (1.f + __expf(-x)); }

__device__ __forceinline__ float fast_tanh(float x) {
  float ax = fabsf(x);
  float e = __expf(-2.f * ax);
  float r = (1.f - e) / (1.f + e);
  return copysignf(r, x);
}

// Build A = [hidden | inputs] as bf16, row-major [4096][2048]
__global__ void pack_x(const float* __restrict__ hidden, const float* __restrict__ inputs,
                       unsigned short* __restrict__ A) {
  int t = blockIdx.x * blockDim.x + threadIdx.x;
  int e = t * 4;
  int m = e >> 11;
  int c = e & 2047;
  const float* src = (c < 1024) ? (hidden + m * 1024 + c) : (inputs + m * 1024 + (c - 1024));
  float4 v = *(const float4*)src;
  ushort4 o;
  o.x = f2bf(v.x);
  o.y = f2bf(v.y);
  o.z = f2bf(v.z);
  o.w = f2bf(v.w);
  *(ushort4*)(A + e) = o;
}

// Transpose each W_g [2048][1024] f32 -> Wt rows [g*1024+u][k] bf16 ([4096][2048])
__global__ void pack_w(const float* __restrict__ Wf, const float* __restrict__ Wi,
                       const float* __restrict__ Wc, const float* __restrict__ Wo,
                       unsigned short* __restrict__ Wt) {
  __shared__ float tile[32][33];
  const int k0 = blockIdx.x * 32;
  const int u0 = blockIdx.y * 32;
  const int g = blockIdx.z;
  const float* W = (g == 0) ? Wf : (g == 1) ? Wi : (g == 2) ? Wc : Wo;
  const int t = threadIdx.x;
  {
    int kk = t >> 3, uu = (t & 7) * 4;
    float4 v = *(const float4*)(W + (k0 + kk) * UDIM + u0 + uu);
    tile[kk][uu + 0] = v.x;
    tile[kk][uu + 1] = v.y;
    tile[kk][uu + 2] = v.z;
    tile[kk][uu + 3] = v.w;
  }
  __syncthreads();
  {
    int ur = t >> 3, k4 = (t & 7) * 4;
    ushort4 o;
    o.x = f2bf(tile[k4 + 0][ur]);
    o.y = f2bf(tile[k4 + 1][ur]);
    o.z = f2bf(tile[k4 + 2][ur]);
    o.w = f2bf(tile[k4 + 3][ur]);
    *(ushort4*)(Wt + (size_t)(g * UDIM + u0 + ur) * KDIM + k0 + k4) = o;
  }
}

// Fused 4-gate GEMM + LSTM epilogue — faithful m201 8-phase port.
// 256x256 tile, BK=64, 2 LDS dbufs (128 KiB), 8 waves (2M x 4N, wave=128x64).
// Per K-step (64): 4 phases {reads 12/4/8/4 ; stage 1 half-tile ; bar ;
// lgkmcnt(0) ; setprio1 ; 16 MFMA quadrant x K=64 ; setprio0 ; [vmcnt(4)] ; bar}.
// Stage FIFO per step: A-half0, B-half0, B-half1, A-half1 (one per phase).
// Wait derivation (steady state, 2 loads/half): end-P4 vmcnt(4) => A0,B0 of next
// step landed; end-P1 vmcnt(4) => B1 landed; end-P2 vmcnt(4) => A1 landed;
// end-P3 none (P4 re-reads B-half0, landed since P1). Loads always issued >=3
// phases before their wait — counted waits never drain.
// LDS halves (16 KiB = 128 rows x 64 k x 2B, row stride 128 B):
//   A-half h packs global rows wr*128 + h*64 + [0,64) at r' = wr*64 + (row&63).
//   B-half h packs gate-rows with nf>>1 == h at r' = wc*32 + (nf&1)*16 + lrow.
// Granule swizzle: k-granule g stored at g ^ (r'&7)  (8x16B granules/row) —
// uniform 8 lanes/bank-quad on ds_read_b128, conflict-free. GLDS source is
// inverse-swizzled; LDS dest linear (rule 21).
__global__ __launch_bounds__(THREADS, 2) void lstm_gemm(
    const unsigned short* __restrict__ A, const unsigned short* __restrict__ Wt,
    const float* __restrict__ bf_, const float* __restrict__ bi_,
    const float* __restrict__ bc_, const float* __restrict__ bo_,
    const float* __restrict__ cell, float* __restrict__ out) {
  extern __shared__ __bf16 lds[];  // 2 dbufs x (A 16384 + B 16384 elems) = 128 KiB

  const int tid = threadIdx.x;
  const int lane = tid & 63;
  const int wid = tid >> 6;
  const int wr = wid >> 2;   // M-half of block
  const int wc = wid & 3;    // N quarter
  const int lrow = lane & 15;
  const int gb = lane >> 4;  // 16B-granule within K=32 sub-slice
  const int l7 = lrow & 7;

  // bijective XCD swizzle over exactly 256 workgroups (1 per CU)
  const int wg = blockIdx.x;
  const int swz = (wg & 7) * 32 + (wg >> 3);
  const int m0 = (swz >> 4) * 256;
  const int bn = swz & 15;  // 64-unit block

  // ---- staging source pointers (inverse-swizzled) ----
  const int t8 = tid >> 3;
  const int gsrc = (tid & 7) ^ (t8 & 7);
  // A half h chunk c: global row m0 + c*128 + h*64 + t8
  const unsigned short* aS00 = A + (size_t)(m0 + t8) * KDIM + gsrc * 8;
  const unsigned short* aS01 = A + (size_t)(m0 + 128 + t8) * KDIM + gsrc * 8;
  const unsigned short* aS10 = A + (size_t)(m0 + 64 + t8) * KDIM + gsrc * 8;
  const unsigned short* aS11 = A + (size_t)(m0 + 192 + t8) * KDIM + gsrc * 8;
  // B half h chunk c: r' = c*64 + t8 -> gate q = h*2+((r'>>4)&1), u = bn*64+(r'>>5)*16+(r'&15)
  int br00, br01, br10, br11;
  {
    int rp0 = t8, rp1 = 64 + t8;
    br00 = (0 * 2 + ((rp0 >> 4) & 1)) * 1024 + bn * 64 + (rp0 >> 5) * 16 + (rp0 & 15);
    br01 = (0 * 2 + ((rp1 >> 4) & 1)) * 1024 + bn * 64 + (rp1 >> 5) * 16 + (rp1 & 15);
    br10 = (1 * 2 + ((rp0 >> 4) & 1)) * 1024 + bn * 64 + (rp0 >> 5) * 16 + (rp0 & 15);
    br11 = (1 * 2 + ((rp1 >> 4) & 1)) * 1024 + bn * 64 + (rp1 >> 5) * 16 + (rp1 & 15);
  }
  const unsigned short* bS00 = Wt + (size_t)br00 * KDIM + gsrc * 8;
  const unsigned short* bS01 = Wt + (size_t)br01 * KDIM + gsrc * 8;
  const unsigned short* bS10 = Wt + (size_t)br10 * KDIM + gsrc * 8;
  const unsigned short* bS11 = Wt + (size_t)br11 * KDIM + gsrc * 8;

  // ---- fragment read base pointers (per dbuf, per kk-half); frag deltas literal ----
  const int sw0 = (gb ^ l7) * 8;
  const int sw1 = ((4 + gb) ^ l7) * 8;
  const __bf16* pA00 = lds + (wr * 64 + lrow) * 64 + sw0;
  const __bf16* pA01 = lds + (wr * 64 + lrow) * 64 + sw1;
  const __bf16* pB00 = lds + 16384 + (wc * 32 + lrow) * 64 + sw0;
  const __bf16* pB01 = lds + 16384 + (wc * 32 + lrow) * 64 + sw1;
  const __bf16* pA10 = pA00 + 32768;
  const __bf16* pA11 = pA01 + 32768;
  const __bf16* pB10 = pB00 + 32768;
  const __bf16* pB11 = pB01 + 32768;

  f32x4 acc[8][4];
#pragma unroll
  for (int mi = 0; mi < 8; ++mi)
#pragma unroll
    for (int nf = 0; nf < 4; ++nf) acc[mi][nf] = (f32x4){0.f, 0.f, 0.f, 0.f};

  bfrag Af[4][2], Ag[4][2], Bf01[2][2], Bf23[2][2];

#define STG_A(ND, H, SS)                                                      \
  do {                                                                        \
    GLDS(aS##H##0 + (SS) * 64, lds + (ND) + (H) * 8192 + tid * 8);            \
    GLDS(aS##H##1 + (SS) * 64, lds + (ND) + (H) * 8192 + 4096 + tid * 8);     \
  } while (0)
#define STG_B(ND, H, SS)                                                          \
  do {                                                                            \
    GLDS(bS##H##0 + (SS) * 64, lds + (ND) + 16384 + (H) * 8192 + tid * 8);        \
    GLDS(bS##H##1 + (SS) * 64, lds + (ND) + 16384 + (H) * 8192 + 4096 + tid * 8); \
  } while (0)

#define VM4 asm volatile("s_waitcnt vmcnt(4)" ::: "memory")
#define VM2 asm volatile("s_waitcnt vmcnt(2)" ::: "memory")
#define VM0 asm volatile("s_waitcnt vmcnt(0)" ::: "memory")

#define PH(CLUSTER, WAIT)                                \
  do {                                                   \
    __builtin_amdgcn_sched_barrier(0);                   \
    __builtin_amdgcn_s_barrier();                        \
    asm volatile("s_waitcnt lgkmcnt(0)" ::: "memory");   \
    __builtin_amdgcn_sched_barrier(0);                   \
    __builtin_amdgcn_s_setprio(1);                       \
    CLUSTER;                                             \
    __builtin_amdgcn_s_setprio(0);                       \
    WAIT;                                                \
    __builtin_amdgcn_s_barrier();                        \
  } while (0)

#define CL8(MB, AF, N0, N1, BF)                                                       \
  _Pragma("unroll") for (int kk = 0; kk < 2; ++kk)                                    \
      _Pragma("unroll") for (int mi = 0; mi < 4; ++mi) {                              \
    acc[(MB) + mi][N0] = __builtin_amdgcn_mfma_f32_16x16x32_bf16(                     \
        AF[mi][kk], BF[0][kk], acc[(MB) + mi][N0], 0, 0, 0);                          \
    acc[(MB) + mi][N1] = __builtin_amdgcn_mfma_f32_16x16x32_bf16(                     \
        AF[mi][kk], BF[1][kk], acc[(MB) + mi][N1], 0, 0, 0);                          \
  }

#define KSTEP(PA0, PA1, PB0, PB1, ND, SS, STG, W1, W2, W4)          \
  do {                                                              \
    /* P1: A0-3 (8 reads) + B0-1 (4); stage A-half0 */              \
    _Pragma("unroll") for (int mi = 0; mi < 4; ++mi) {              \
      Af[mi][0] = *(const bfrag*)((PA0) + mi * 1024);               \
      Af[mi][1] = *(const bfrag*)((PA1) + mi * 1024);               \
    }                                                               \
    _Pragma("unroll") for (int nf = 0; nf < 2; ++nf) {              \
      Bf01[nf][0] = *(const bfrag*)((PB0) + nf * 1024);             \
      Bf01[nf][1] = *(const bfrag*)((PB1) + nf * 1024);             \
    }                                                               \
    if (STG) STG_A(ND, 0, SS);                                      \
    PH(CL8(0, Af, 0, 1, Bf01), W1);                                 \
    /* P2: B2-3 (4); stage B-half0 */                               \
    _Pragma("unroll") for (int nf = 0; nf < 2; ++nf) {              \
      Bf23[nf][0] = *(const bfrag*)((PB0) + 8192 + nf * 1024);      \
      Bf23[nf][1] = *(const bfrag*)((PB1) + 8192 + nf * 1024);      \
    }                                                               \
    if (STG) STG_B(ND, 0, SS);                                      \
    PH(CL8(0, Af, 2, 3, Bf23), W2);                                 \
    /* P3: A4-7 (8); stage B-half1 */                               \
    _Pragma("unroll") for (int mi = 0; mi < 4; ++mi) {              \
      Ag[mi][0] = *(const bfrag*)((PA0) + 8192 + mi * 1024);        \
      Ag[mi][1] = *(const bfrag*)((PA1) + 8192 + mi * 1024);        \
    }                                                               \
    if (STG) STG_B(ND, 1, SS);                                      \
    PH(CL8(4, Ag, 2, 3, Bf23), ((void)0));                          \
    /* P4: re-read B0-1 (4); stage A-half1 */                       \
    _Pragma("unroll") for (int nf = 0; nf < 2; ++nf) {              \
      Bf01[nf][0] = *(const bfrag*)((PB0) + nf * 1024);             \
      Bf01[nf][1] = *(const bfrag*)((PB1) + nf * 1024);             \
    }                                                               \
    if (STG) STG_A(ND, 1, SS);                                      \
    PH(CL8(4, Ag, 0, 1, Bf01), W4);                                 \
  } while (0)

  // prologue: stage step 0 into dbuf0 in FIFO order {A0, B0, B1, A1}
  STG_A(0, 0, 0);
  STG_B(0, 0, 0);
  STG_B(0, 1, 0);
  STG_A(0, 1, 0);
  VM4;  // A0,B0 landed
  __builtin_amdgcn_s_barrier();

  for (int su = 0; su < 15; ++su) {  // K-steps 0..29
    KSTEP(pA00, pA01, pB00, pB01, 32768, 2 * su + 1, 1, VM4, VM4, VM4);
    KSTEP(pA10, pA11, pB10, pB11, 0, 2 * su + 2, 1, VM4, VM4, VM4);
  }
  KSTEP(pA00, pA01, pB00, pB01, 32768, 31, 1, VM4, VM4, VM4);  // step 30
  KSTEP(pA10, pA11, pB10, pB11, 0, 0, 0, VM2, VM0, ((void)0)); // step 31 (tail)

  // ---- epilogue: per lane, 4 nf-fragments = the 4 gates of one unit u ----
  const int u = bn * 64 + wc * 16 + lrow;
  const float fb = bf_[u], ib = bi_[u], cb = bc_[u], ob = bo_[u];
  const int rbase = m0 + wr * 128 + (lane >> 4) * 4;
#pragma unroll
  for (int mi = 0; mi < 8; ++mi) {
#pragma unroll
    for (int j = 0; j < 4; ++j) {
      const int m = rbase + mi * 16 + j;
      float pf = acc[mi][0][j] + fb;
      float pi = acc[mi][1][j] + ib;
      float pc = acc[mi][2][j] + cb;
      float po = acc[mi][3][j] + ob;
      float fg = fast_sigmoid(pf);
      float ig = fast_sigmoid(pi);
      float cc = fast_tanh(pc);
      float og = fast_sigmoid(po);
      float cold = cell[(size_t)m * UDIM + u];
      float cnew = fg * cold + ig * cc;
      out[(size_t)m * UDIM + u] = og * fast_tanh(cnew);
      out[CMOFF + (size_t)m * UDIM + u] = cnew;
    }
  }
}

extern "C" void kernel_launch(void* const* d_in, const int* in_sizes, int n_in,
                              void* d_out, int out_size, void* d_ws, size_t ws_size,
                              hipStream_t stream) {
  const float* inputs = (const float*)d_in[0];
  const float* hidden = (const float*)d_in[1];
  const float* cell = (const float*)d_in[2];
  const float* Wf = (const float*)d_in[3];
  const float* bf = (const float*)d_in[4];
  const float* Wi = (const float*)d_in[5];
  const float* bi = (const float*)d_in[6];
  const float* Wc = (const float*)d_in[7];
  const float* bc = (const float*)d_in[8];
  const float* Wo = (const float*)d_in[9];
  const float* bo = (const float*)d_in[10];
  float* out = (float*)d_out;

  unsigned short* Abf = (unsigned short*)d_ws;     // [4096][2048] bf16 = 16 MB
  unsigned short* Wt = Abf + (size_t)MDIM * KDIM;  // [4096][2048] bf16 = 16 MB

  pack_x<<<(MDIM * KDIM / 4) / 256, 256, 0, stream>>>(hidden, inputs, Abf);
  pack_w<<<dim3(KDIM / 32, UDIM / 32, 4), 256, 0, stream>>>(Wf, Wi, Wc, Wo, Wt);
  lstm_gemm<<<dim3(256), dim3(THREADS), 131072, stream>>>(Abf, Wt, bf, bi, bc, bo, cell, out);
}